// Round 3
// baseline (4458.561 us; speedup 1.0000x reference)
//
#include <hip/hip_runtime.h>
#include <cmath>

#define NPTS  200000
#define KNBR  16
#define MROWS 3200000   // NPTS*KNBR
#define EPSB  1e-5f

__device__ __forceinline__ float gelu_f(float x) {
    return 0.5f * x * (1.0f + erff(x * 0.70710678118654752f));
}

// ---------------- stats over y1 = x @ w1 (16 ch) ----------------
__global__ __launch_bounds__(256) void k_stats1(
    const float* __restrict__ p, const float4* __restrict__ f,
    const int* __restrict__ gidx, const float* __restrict__ w1,
    float* __restrict__ stats)
{
    __shared__ __align__(16) float w1s[112];
    __shared__ float red[4 * 32];
    for (int i = threadIdx.x; i < 112; i += 256) w1s[i] = w1[i];
    __syncthreads();
    const float4* w1v = (const float4*)w1s;   // [7][4]

    float acc[32];
#pragma unroll
    for (int c = 0; c < 32; c++) acc[c] = 0.f;

    int stride = gridDim.x * 256;
    for (int r = blockIdx.x * 256 + threadIdx.x; r < MROWS; r += stride) {
        int n = r >> 4;
        int idx = gidx[r];
        float4 fv = f[idx];
        float x[7];
        x[0] = p[idx * 3 + 0] - p[n * 3 + 0];
        x[1] = p[idx * 3 + 1] - p[n * 3 + 1];
        x[2] = p[idx * 3 + 2] - p[n * 3 + 2];
        x[3] = fv.x; x[4] = fv.y; x[5] = fv.z; x[6] = fv.w;
#pragma unroll
        for (int j0 = 0; j0 < 16; j0 += 4) {
            float y0 = 0.f, y1 = 0.f, y2 = 0.f, y3 = 0.f;
#pragma unroll
            for (int i = 0; i < 7; i++) {
                float4 w = w1v[i * 4 + (j0 >> 2)];
                float xi = x[i];
                y0 = fmaf(xi, w.x, y0); y1 = fmaf(xi, w.y, y1);
                y2 = fmaf(xi, w.z, y2); y3 = fmaf(xi, w.w, y3);
            }
            acc[j0 + 0] += y0; acc[16 + j0 + 0] += y0 * y0;
            acc[j0 + 1] += y1; acc[16 + j0 + 1] += y1 * y1;
            acc[j0 + 2] += y2; acc[16 + j0 + 2] += y2 * y2;
            acc[j0 + 3] += y3; acc[16 + j0 + 3] += y3 * y3;
        }
    }
    int lane = threadIdx.x & 63, wv = threadIdx.x >> 6;
#pragma unroll
    for (int c = 0; c < 32; c++) {
        float v = acc[c];
        v += __shfl_down(v, 32); v += __shfl_down(v, 16); v += __shfl_down(v, 8);
        v += __shfl_down(v, 4);  v += __shfl_down(v, 2);  v += __shfl_down(v, 1);
        if (lane == 0) red[wv * 32 + c] = v;
    }
    __syncthreads();
    for (int c = threadIdx.x; c < 32; c += 256)
        atomicAdd(&stats[c], red[c] + red[32 + c] + red[64 + c] + red[96 + c]);
}

// ---------------- stats over y2 = gelu(bn(y1)) @ w2 (32 ch) ----------------
__global__ __launch_bounds__(256) void k_stats2(
    const float* __restrict__ p, const float4* __restrict__ f,
    const int* __restrict__ gidx, const float* __restrict__ w1,
    const float* __restrict__ w2, const float* __restrict__ scsh1,
    float* __restrict__ stats)
{
    __shared__ __align__(16) float w1s[112];
    __shared__ __align__(16) float w2s[512];
    __shared__ float sc1s[16], sh1s[16];
    __shared__ float red[4 * 64];
    for (int i = threadIdx.x; i < 112; i += 256) w1s[i] = w1[i];
    for (int i = threadIdx.x; i < 512; i += 256) w2s[i] = w2[i];
    if (threadIdx.x < 16) {
        sc1s[threadIdx.x] = scsh1[threadIdx.x];
        sh1s[threadIdx.x] = scsh1[16 + threadIdx.x];
    }
    __syncthreads();
    const float4* w1v = (const float4*)w1s;   // [7][4]
    const float4* w2v = (const float4*)w2s;   // [16][8]

    float acc[64];
#pragma unroll
    for (int c = 0; c < 64; c++) acc[c] = 0.f;

    int stride = gridDim.x * 256;
    for (int r = blockIdx.x * 256 + threadIdx.x; r < MROWS; r += stride) {
        int n = r >> 4;
        int idx = gidx[r];
        float4 fv = f[idx];
        float x[7];
        x[0] = p[idx * 3 + 0] - p[n * 3 + 0];
        x[1] = p[idx * 3 + 1] - p[n * 3 + 1];
        x[2] = p[idx * 3 + 2] - p[n * 3 + 2];
        x[3] = fv.x; x[4] = fv.y; x[5] = fv.z; x[6] = fv.w;
        float h1[16];
#pragma unroll
        for (int j0 = 0; j0 < 16; j0 += 4) {
            float y0 = 0.f, y1 = 0.f, y2 = 0.f, y3 = 0.f;
#pragma unroll
            for (int i = 0; i < 7; i++) {
                float4 w = w1v[i * 4 + (j0 >> 2)];
                float xi = x[i];
                y0 = fmaf(xi, w.x, y0); y1 = fmaf(xi, w.y, y1);
                y2 = fmaf(xi, w.z, y2); y3 = fmaf(xi, w.w, y3);
            }
            h1[j0 + 0] = gelu_f(fmaf(y0, sc1s[j0 + 0], sh1s[j0 + 0]));
            h1[j0 + 1] = gelu_f(fmaf(y1, sc1s[j0 + 1], sh1s[j0 + 1]));
            h1[j0 + 2] = gelu_f(fmaf(y2, sc1s[j0 + 2], sh1s[j0 + 2]));
            h1[j0 + 3] = gelu_f(fmaf(y3, sc1s[j0 + 3], sh1s[j0 + 3]));
        }
#pragma unroll
        for (int j0 = 0; j0 < 32; j0 += 4) {
            float y0 = 0.f, y1 = 0.f, y2 = 0.f, y3 = 0.f;
#pragma unroll
            for (int i = 0; i < 16; i++) {
                float4 w = w2v[i * 8 + (j0 >> 2)];
                float hi = h1[i];
                y0 = fmaf(hi, w.x, y0); y1 = fmaf(hi, w.y, y1);
                y2 = fmaf(hi, w.z, y2); y3 = fmaf(hi, w.w, y3);
            }
            acc[j0 + 0] += y0; acc[32 + j0 + 0] += y0 * y0;
            acc[j0 + 1] += y1; acc[32 + j0 + 1] += y1 * y1;
            acc[j0 + 2] += y2; acc[32 + j0 + 2] += y2 * y2;
            acc[j0 + 3] += y3; acc[32 + j0 + 3] += y3 * y3;
        }
    }
    int lane = threadIdx.x & 63, wv = threadIdx.x >> 6;
#pragma unroll
    for (int c = 0; c < 64; c++) {
        float v = acc[c];
        v += __shfl_down(v, 32); v += __shfl_down(v, 16); v += __shfl_down(v, 8);
        v += __shfl_down(v, 4);  v += __shfl_down(v, 2);  v += __shfl_down(v, 1);
        if (lane == 0) red[wv * 64 + c] = v;
    }
    __syncthreads();
    for (int c = threadIdx.x; c < 64; c += 256)
        atomicAdd(&stats[c], red[c] + red[64 + c] + red[128 + c] + red[192 + c]);
}

// BN finalize: scale/shift from sum/sumsq
__global__ void k_finalize(const float* __restrict__ stats, const float* __restrict__ g,
                           const float* __restrict__ b, float* __restrict__ scsh,
                           int H, float invM)
{
    int j = threadIdx.x;
    if (j < H) {
        float m = stats[j] * invM;
        float v = stats[H + j] * invM - m * m;
        float sc = g[j] * rsqrtf(v + EPSB);
        scsh[j] = sc;
        scsh[H + j] = fmaf(-m, sc, b[j]);
    }
}

// ---------------- full MLP, TWO rows per thread sharing all weight reads.
// Row A = it*1.6M + b*256 + t, row B = A + 0.8M. 16-lane groups own one
// point per row-set; max-pool via shfl_xor butterfly; lane keeps 4 channels.
// 3125 blocks * 256 thr * 2 its * 2 rows == 3,200,000 rows exactly.
__global__ __launch_bounds__(256, 4) void k_pool2(
    const float* __restrict__ p, const float4* __restrict__ f,
    const int* __restrict__ gidx,
    const float* __restrict__ w1, const float* __restrict__ w2,
    const float* __restrict__ w3,
    const float* __restrict__ scsh1, const float* __restrict__ scsh2,
    float* __restrict__ stats, float* __restrict__ pooled)
{
    __shared__ __align__(16) float w1s[112];
    __shared__ __align__(16) float w2s[512];
    __shared__ __align__(16) float w3s[2048];
    __shared__ float sc1s[16], sh1s[16], sc2s[32], sh2s[32];
    __shared__ float reds[256];
    __shared__ float redq[256];
    int tid = threadIdx.x;
    for (int i = tid; i < 112; i += 256) w1s[i] = w1[i];
    for (int i = tid; i < 512; i += 256) w2s[i] = w2[i];
    for (int i = tid; i < 2048; i += 256) w3s[i] = w3[i];
    if (tid < 16) { sc1s[tid] = scsh1[tid]; sh1s[tid] = scsh1[16 + tid]; }
    if (tid < 32) { sc2s[tid] = scsh2[tid]; sh2s[tid] = scsh2[32 + tid]; }
    __syncthreads();

    const float4* w1v = (const float4*)w1s;   // [7][4]
    const float4* w2v = (const float4*)w2s;   // [16][8]
    const float4* w3v = (const float4*)w3s;   // [32][16]

    int lane = tid & 63;
    int sub  = lane & 15;   // this lane keeps channels [4*sub, 4*sub+3]

    float s0 = 0.f, s1 = 0.f, s2 = 0.f, s3 = 0.f;
    float q0 = 0.f, q1 = 0.f, q2 = 0.f, q3 = 0.f;

#pragma unroll 1
    for (int it = 0; it < 2; it++) {
        int rA = it * 1600000 + blockIdx.x * 256 + tid;
        int rB = rA + 800000;
        int nA = rA >> 4, nB = rB >> 4;
        int idxA = gidx[rA], idxB = gidx[rB];
        float4 fvA = f[idxA];
        float4 fvB = f[idxB];
        float xA[7], xB[7];
        xA[0] = p[idxA * 3 + 0] - p[nA * 3 + 0];
        xA[1] = p[idxA * 3 + 1] - p[nA * 3 + 1];
        xA[2] = p[idxA * 3 + 2] - p[nA * 3 + 2];
        xA[3] = fvA.x; xA[4] = fvA.y; xA[5] = fvA.z; xA[6] = fvA.w;
        xB[0] = p[idxB * 3 + 0] - p[nB * 3 + 0];
        xB[1] = p[idxB * 3 + 1] - p[nB * 3 + 1];
        xB[2] = p[idxB * 3 + 2] - p[nB * 3 + 2];
        xB[3] = fvB.x; xB[4] = fvB.y; xB[5] = fvB.z; xB[6] = fvB.w;

        // ---- layer 1 (7 -> 16), shared weight reads ----
        float h1A[16], h1B[16];
#pragma unroll
        for (int j0 = 0; j0 < 16; j0 += 4) {
            float a0 = 0.f, a1 = 0.f, a2 = 0.f, a3 = 0.f;
            float b0 = 0.f, b1 = 0.f, b2 = 0.f, b3 = 0.f;
#pragma unroll
            for (int i = 0; i < 7; i++) {
                float4 w = w1v[i * 4 + (j0 >> 2)];
                float xa = xA[i], xb = xB[i];
                a0 = fmaf(xa, w.x, a0); a1 = fmaf(xa, w.y, a1);
                a2 = fmaf(xa, w.z, a2); a3 = fmaf(xa, w.w, a3);
                b0 = fmaf(xb, w.x, b0); b1 = fmaf(xb, w.y, b1);
                b2 = fmaf(xb, w.z, b2); b3 = fmaf(xb, w.w, b3);
            }
            h1A[j0 + 0] = gelu_f(fmaf(a0, sc1s[j0 + 0], sh1s[j0 + 0]));
            h1A[j0 + 1] = gelu_f(fmaf(a1, sc1s[j0 + 1], sh1s[j0 + 1]));
            h1A[j0 + 2] = gelu_f(fmaf(a2, sc1s[j0 + 2], sh1s[j0 + 2]));
            h1A[j0 + 3] = gelu_f(fmaf(a3, sc1s[j0 + 3], sh1s[j0 + 3]));
            h1B[j0 + 0] = gelu_f(fmaf(b0, sc1s[j0 + 0], sh1s[j0 + 0]));
            h1B[j0 + 1] = gelu_f(fmaf(b1, sc1s[j0 + 1], sh1s[j0 + 1]));
            h1B[j0 + 2] = gelu_f(fmaf(b2, sc1s[j0 + 2], sh1s[j0 + 2]));
            h1B[j0 + 3] = gelu_f(fmaf(b3, sc1s[j0 + 3], sh1s[j0 + 3]));
        }

        // ---- layer 2 (16 -> 32), shared weight reads ----
        float h2A[32], h2B[32];
#pragma unroll
        for (int j0 = 0; j0 < 32; j0 += 4) {
            float a0 = 0.f, a1 = 0.f, a2 = 0.f, a3 = 0.f;
            float b0 = 0.f, b1 = 0.f, b2 = 0.f, b3 = 0.f;
#pragma unroll
            for (int i = 0; i < 16; i++) {
                float4 w = w2v[i * 8 + (j0 >> 2)];
                float ha = h1A[i], hb = h1B[i];
                a0 = fmaf(ha, w.x, a0); a1 = fmaf(ha, w.y, a1);
                a2 = fmaf(ha, w.z, a2); a3 = fmaf(ha, w.w, a3);
                b0 = fmaf(hb, w.x, b0); b1 = fmaf(hb, w.y, b1);
                b2 = fmaf(hb, w.z, b2); b3 = fmaf(hb, w.w, b3);
            }
            h2A[j0 + 0] = gelu_f(fmaf(a0, sc2s[j0 + 0], sh2s[j0 + 0]));
            h2A[j0 + 1] = gelu_f(fmaf(a1, sc2s[j0 + 1], sh2s[j0 + 1]));
            h2A[j0 + 2] = gelu_f(fmaf(a2, sc2s[j0 + 2], sh2s[j0 + 2]));
            h2A[j0 + 3] = gelu_f(fmaf(a3, sc2s[j0 + 3], sh2s[j0 + 3]));
            h2B[j0 + 0] = gelu_f(fmaf(b0, sc2s[j0 + 0], sh2s[j0 + 0]));
            h2B[j0 + 1] = gelu_f(fmaf(b1, sc2s[j0 + 1], sh2s[j0 + 1]));
            h2B[j0 + 2] = gelu_f(fmaf(b2, sc2s[j0 + 2], sh2s[j0 + 2]));
            h2B[j0 + 3] = gelu_f(fmaf(b3, sc2s[j0 + 3], sh2s[j0 + 3]));
        }

        // ---- layer 3 (32 -> 64) + 16-lane max-pool, shared weight reads ----
        float pvA0 = 0.f, pvA1 = 0.f, pvA2 = 0.f, pvA3 = 0.f;
        float pvB0 = 0.f, pvB1 = 0.f, pvB2 = 0.f, pvB3 = 0.f;
#pragma unroll
        for (int c = 0; c < 16; c++) {
            float a0 = 0.f, a1 = 0.f, a2 = 0.f, a3 = 0.f;
            float b0 = 0.f, b1 = 0.f, b2 = 0.f, b3 = 0.f;
#pragma unroll
            for (int i = 0; i < 32; i++) {
                float4 w = w3v[i * 16 + c];
                float ha = h2A[i], hb = h2B[i];
                a0 = fmaf(ha, w.x, a0); a1 = fmaf(ha, w.y, a1);
                a2 = fmaf(ha, w.z, a2); a3 = fmaf(ha, w.w, a3);
                b0 = fmaf(hb, w.x, b0); b1 = fmaf(hb, w.y, b1);
                b2 = fmaf(hb, w.z, b2); b3 = fmaf(hb, w.w, b3);
            }
#pragma unroll
            for (int m = 1; m <= 8; m <<= 1) {
                a0 = fmaxf(a0, __shfl_xor(a0, m));
                a1 = fmaxf(a1, __shfl_xor(a1, m));
                a2 = fmaxf(a2, __shfl_xor(a2, m));
                a3 = fmaxf(a3, __shfl_xor(a3, m));
                b0 = fmaxf(b0, __shfl_xor(b0, m));
                b1 = fmaxf(b1, __shfl_xor(b1, m));
                b2 = fmaxf(b2, __shfl_xor(b2, m));
                b3 = fmaxf(b3, __shfl_xor(b3, m));
            }
            if (sub == c) {
                pvA0 = a0; pvA1 = a1; pvA2 = a2; pvA3 = a3;
                pvB0 = b0; pvB1 = b1; pvB2 = b2; pvB3 = b3;
            }
        }
        // 16 lanes cover each point's 64 channels contiguously -> coalesced
        *(float4*)&pooled[(size_t)nA * 64 + sub * 4] = make_float4(pvA0, pvA1, pvA2, pvA3);
        *(float4*)&pooled[(size_t)nB * 64 + sub * 4] = make_float4(pvB0, pvB1, pvB2, pvB3);
        s0 += pvA0 + pvB0; q0 = fmaf(pvA0, pvA0, fmaf(pvB0, pvB0, q0));
        s1 += pvA1 + pvB1; q1 = fmaf(pvA1, pvA1, fmaf(pvB1, pvB1, q1));
        s2 += pvA2 + pvB2; q2 = fmaf(pvA2, pvA2, fmaf(pvB2, pvB2, q2));
        s3 += pvA3 + pvB3; q3 = fmaf(pvA3, pvA3, fmaf(pvB3, pvB3, q3));
    }

    // fold lanes l+16,l+32,l+48 into lanes 0..15 (same channel set)
    s0 += __shfl_down(s0, 32); s0 += __shfl_down(s0, 16);
    s1 += __shfl_down(s1, 32); s1 += __shfl_down(s1, 16);
    s2 += __shfl_down(s2, 32); s2 += __shfl_down(s2, 16);
    s3 += __shfl_down(s3, 32); s3 += __shfl_down(s3, 16);
    q0 += __shfl_down(q0, 32); q0 += __shfl_down(q0, 16);
    q1 += __shfl_down(q1, 32); q1 += __shfl_down(q1, 16);
    q2 += __shfl_down(q2, 32); q2 += __shfl_down(q2, 16);
    q3 += __shfl_down(q3, 32); q3 += __shfl_down(q3, 16);
    int wv = tid >> 6;
    if (lane < 16) {
        reds[wv * 64 + sub * 4 + 0] = s0;
        reds[wv * 64 + sub * 4 + 1] = s1;
        reds[wv * 64 + sub * 4 + 2] = s2;
        reds[wv * 64 + sub * 4 + 3] = s3;
        redq[wv * 64 + sub * 4 + 0] = q0;
        redq[wv * 64 + sub * 4 + 1] = q1;
        redq[wv * 64 + sub * 4 + 2] = q2;
        redq[wv * 64 + sub * 4 + 3] = q3;
    }
    __syncthreads();
    if (tid < 64) {
        atomicAdd(&stats[tid],
                  reds[tid] + reds[64 + tid] + reds[128 + tid] + reds[192 + tid]);
        atomicAdd(&stats[64 + tid],
                  redq[tid] + redq[64 + tid] + redq[128 + tid] + redq[192 + tid]);
    }
}

// double-BN collapse: z = a1*(y-m)+b_nbr has mean b_nbr, var a1^2*v exactly
__global__ void k_fin3(const float* __restrict__ stats,
                       const float* __restrict__ g_nbr, const float* __restrict__ g_post,
                       const float* __restrict__ b_post, float* __restrict__ scsh)
{
    int j = threadIdx.x;
    if (j < 64) {
        float m = stats[j] * (1.0f / NPTS);
        float v = stats[64 + j] * (1.0f / NPTS) - m * m;
        float a1 = g_nbr[j] * rsqrtf(v + EPSB);
        float s3 = g_post[j] * a1 * rsqrtf(fmaf(a1 * a1, v, EPSB));
        scsh[j] = s3;
        scsh[64 + j] = fmaf(-m, s3, b_post[j]);
    }
}

// ---------------- head: (N x 64) @ (64 x 256) ----------------
__global__ __launch_bounds__(256) void k_head(
    const float* __restrict__ pooled, const float* __restrict__ scsh3,
    const float* __restrict__ wpost, float* __restrict__ out)
{
    __shared__ float rowbuf[512];
    __shared__ float s3s[64], c3s[64];
    int tid = threadIdx.x;
    if (tid < 64) { s3s[tid] = scsh3[tid]; c3s[tid] = scsh3[64 + tid]; }
    float wcol[64];
#pragma unroll
    for (int j = 0; j < 64; j++) wcol[j] = wpost[j * 256 + tid];
    __syncthreads();

    const int nchunks = NPTS / 8;  // 25000
    for (int c = blockIdx.x; c < nchunks; c += gridDim.x) {
        int n0 = c * 8;
#pragma unroll
        for (int t = tid; t < 512; t += 256) {
            int rr = t >> 6, j = t & 63;
            rowbuf[t] = fmaf(pooled[(size_t)(n0 + rr) * 64 + j], s3s[j], c3s[j]);
        }
        __syncthreads();
#pragma unroll
        for (int rr = 0; rr < 8; rr++) {
            float acc = 0.f;
#pragma unroll
            for (int j = 0; j < 64; j++) acc = fmaf(rowbuf[rr * 64 + j], wcol[j], acc);
            out[(size_t)(n0 + rr) * 256 + tid] = acc;
        }
        __syncthreads();
    }
}

extern "C" void kernel_launch(void* const* d_in, const int* in_sizes, int n_in,
                              void* d_out, int out_size, void* d_ws, size_t ws_size,
                              hipStream_t stream)
{
    const float*  p    = (const float*)d_in[0];
    const float4* f    = (const float4*)d_in[1];
    const int*    gidx = (const int*)d_in[2];
    const float*  w1   = (const float*)d_in[3];
    const float*  g1   = (const float*)d_in[4];
    const float*  b1   = (const float*)d_in[5];
    const float*  w2   = (const float*)d_in[6];
    const float*  g2   = (const float*)d_in[7];
    const float*  b2   = (const float*)d_in[8];
    const float*  w3   = (const float*)d_in[9];
    const float*  gn   = (const float*)d_in[10];
    // d_in[11] = b_nbr: cancels exactly in the collapsed double-BN
    const float*  gp   = (const float*)d_in[12];
    const float*  bp   = (const float*)d_in[13];
    const float*  wp   = (const float*)d_in[14];
    float* out = (float*)d_out;
    float* ws  = (float*)d_ws;

    float* stats1 = ws;        float* scsh1 = ws + 32;
    float* stats2 = ws + 64;   float* scsh2 = ws + 128;
    float* stats3 = ws + 192;  float* scsh3 = ws + 320;
    float* pooled = ws + 1024;

    hipMemsetAsync(d_ws, 0, 2048, stream);
    k_stats1<<<2048, 256, 0, stream>>>(p, f, gidx, w1, stats1);
    k_finalize<<<1, 64, 0, stream>>>(stats1, g1, b1, scsh1, 16, 1.0f / (float)MROWS);
    k_stats2<<<2048, 256, 0, stream>>>(p, f, gidx, w1, w2, scsh1, stats2);
    k_finalize<<<1, 64, 0, stream>>>(stats2, g2, b2, scsh2, 32, 1.0f / (float)MROWS);
    k_pool2<<<3125, 256, 0, stream>>>(p, f, gidx, w1, w2, w3, scsh1, scsh2, stats3, pooled);
    k_fin3<<<1, 64, 0, stream>>>(stats3, gn, gp, bp, scsh3);
    k_head<<<1024, 256, 0, stream>>>(pooled, scsh3, wp, out);
}

// Round 4
// 2998.763 us; speedup vs baseline: 1.4868x; 1.4868x over previous
//
#include <hip/hip_runtime.h>
#include <cmath>

#define NPTS  200000
#define KNBR  16
#define MROWS 3200000   // NPTS*KNBR
#define EPSB  1e-5f

__device__ __forceinline__ float gelu_f(float x) {
    return 0.5f * x * (1.0f + erff(x * 0.70710678118654752f));
}

// ---------------- stats over y1 = x @ w1 (16 ch) ----------------
__global__ __launch_bounds__(256) void k_stats1(
    const float* __restrict__ p, const float4* __restrict__ f,
    const int* __restrict__ gidx, const float* __restrict__ w1,
    float* __restrict__ stats)
{
    __shared__ __align__(16) float w1s[112];
    __shared__ float red[4 * 32];
    for (int i = threadIdx.x; i < 112; i += 256) w1s[i] = w1[i];
    __syncthreads();
    const float4* w1v = (const float4*)w1s;   // [7][4]

    float acc[32];
#pragma unroll
    for (int c = 0; c < 32; c++) acc[c] = 0.f;

    int stride = gridDim.x * 256;
    for (int r = blockIdx.x * 256 + threadIdx.x; r < MROWS; r += stride) {
        int n = r >> 4;
        int idx = gidx[r];
        float4 fv = f[idx];
        float x[7];
        x[0] = p[idx * 3 + 0] - p[n * 3 + 0];
        x[1] = p[idx * 3 + 1] - p[n * 3 + 1];
        x[2] = p[idx * 3 + 2] - p[n * 3 + 2];
        x[3] = fv.x; x[4] = fv.y; x[5] = fv.z; x[6] = fv.w;
#pragma unroll
        for (int j0 = 0; j0 < 16; j0 += 4) {
            float y0 = 0.f, y1 = 0.f, y2 = 0.f, y3 = 0.f;
#pragma unroll
            for (int i = 0; i < 7; i++) {
                float4 w = w1v[i * 4 + (j0 >> 2)];
                float xi = x[i];
                y0 = fmaf(xi, w.x, y0); y1 = fmaf(xi, w.y, y1);
                y2 = fmaf(xi, w.z, y2); y3 = fmaf(xi, w.w, y3);
            }
            acc[j0 + 0] += y0; acc[16 + j0 + 0] += y0 * y0;
            acc[j0 + 1] += y1; acc[16 + j0 + 1] += y1 * y1;
            acc[j0 + 2] += y2; acc[16 + j0 + 2] += y2 * y2;
            acc[j0 + 3] += y3; acc[16 + j0 + 3] += y3 * y3;
        }
    }
    int lane = threadIdx.x & 63, wv = threadIdx.x >> 6;
#pragma unroll
    for (int c = 0; c < 32; c++) {
        float v = acc[c];
        v += __shfl_down(v, 32); v += __shfl_down(v, 16); v += __shfl_down(v, 8);
        v += __shfl_down(v, 4);  v += __shfl_down(v, 2);  v += __shfl_down(v, 1);
        if (lane == 0) red[wv * 32 + c] = v;
    }
    __syncthreads();
    for (int c = threadIdx.x; c < 32; c += 256)
        atomicAdd(&stats[c], red[c] + red[32 + c] + red[64 + c] + red[96 + c]);
}

// ---------------- stats over y2 = gelu(bn(y1)) @ w2 (32 ch) ----------------
__global__ __launch_bounds__(256) void k_stats2(
    const float* __restrict__ p, const float4* __restrict__ f,
    const int* __restrict__ gidx, const float* __restrict__ w1,
    const float* __restrict__ w2, const float* __restrict__ scsh1,
    float* __restrict__ stats)
{
    __shared__ __align__(16) float w1s[112];
    __shared__ __align__(16) float w2s[512];
    __shared__ float sc1s[16], sh1s[16];
    __shared__ float red[4 * 64];
    for (int i = threadIdx.x; i < 112; i += 256) w1s[i] = w1[i];
    for (int i = threadIdx.x; i < 512; i += 256) w2s[i] = w2[i];
    if (threadIdx.x < 16) {
        sc1s[threadIdx.x] = scsh1[threadIdx.x];
        sh1s[threadIdx.x] = scsh1[16 + threadIdx.x];
    }
    __syncthreads();
    const float4* w1v = (const float4*)w1s;   // [7][4]
    const float4* w2v = (const float4*)w2s;   // [16][8]

    float acc[64];
#pragma unroll
    for (int c = 0; c < 64; c++) acc[c] = 0.f;

    int stride = gridDim.x * 256;
    for (int r = blockIdx.x * 256 + threadIdx.x; r < MROWS; r += stride) {
        int n = r >> 4;
        int idx = gidx[r];
        float4 fv = f[idx];
        float x[7];
        x[0] = p[idx * 3 + 0] - p[n * 3 + 0];
        x[1] = p[idx * 3 + 1] - p[n * 3 + 1];
        x[2] = p[idx * 3 + 2] - p[n * 3 + 2];
        x[3] = fv.x; x[4] = fv.y; x[5] = fv.z; x[6] = fv.w;
        float h1[16];
#pragma unroll
        for (int j0 = 0; j0 < 16; j0 += 4) {
            float y0 = 0.f, y1 = 0.f, y2 = 0.f, y3 = 0.f;
#pragma unroll
            for (int i = 0; i < 7; i++) {
                float4 w = w1v[i * 4 + (j0 >> 2)];
                float xi = x[i];
                y0 = fmaf(xi, w.x, y0); y1 = fmaf(xi, w.y, y1);
                y2 = fmaf(xi, w.z, y2); y3 = fmaf(xi, w.w, y3);
            }
            h1[j0 + 0] = gelu_f(fmaf(y0, sc1s[j0 + 0], sh1s[j0 + 0]));
            h1[j0 + 1] = gelu_f(fmaf(y1, sc1s[j0 + 1], sh1s[j0 + 1]));
            h1[j0 + 2] = gelu_f(fmaf(y2, sc1s[j0 + 2], sh1s[j0 + 2]));
            h1[j0 + 3] = gelu_f(fmaf(y3, sc1s[j0 + 3], sh1s[j0 + 3]));
        }
#pragma unroll
        for (int j0 = 0; j0 < 32; j0 += 4) {
            float y0 = 0.f, y1 = 0.f, y2 = 0.f, y3 = 0.f;
#pragma unroll
            for (int i = 0; i < 16; i++) {
                float4 w = w2v[i * 8 + (j0 >> 2)];
                float hi = h1[i];
                y0 = fmaf(hi, w.x, y0); y1 = fmaf(hi, w.y, y1);
                y2 = fmaf(hi, w.z, y2); y3 = fmaf(hi, w.w, y3);
            }
            acc[j0 + 0] += y0; acc[32 + j0 + 0] += y0 * y0;
            acc[j0 + 1] += y1; acc[32 + j0 + 1] += y1 * y1;
            acc[j0 + 2] += y2; acc[32 + j0 + 2] += y2 * y2;
            acc[j0 + 3] += y3; acc[32 + j0 + 3] += y3 * y3;
        }
    }
    int lane = threadIdx.x & 63, wv = threadIdx.x >> 6;
#pragma unroll
    for (int c = 0; c < 64; c++) {
        float v = acc[c];
        v += __shfl_down(v, 32); v += __shfl_down(v, 16); v += __shfl_down(v, 8);
        v += __shfl_down(v, 4);  v += __shfl_down(v, 2);  v += __shfl_down(v, 1);
        if (lane == 0) red[wv * 64 + c] = v;
    }
    __syncthreads();
    for (int c = threadIdx.x; c < 64; c += 256)
        atomicAdd(&stats[c], red[c] + red[64 + c] + red[128 + c] + red[192 + c]);
}

// BN finalize: scale/shift from sum/sumsq
__global__ void k_finalize(const float* __restrict__ stats, const float* __restrict__ g,
                           const float* __restrict__ b, float* __restrict__ scsh,
                           int H, float invM)
{
    int j = threadIdx.x;
    if (j < H) {
        float m = stats[j] * invM;
        float v = stats[H + j] * invM - m * m;
        float sc = g[j] * rsqrtf(v + EPSB);
        scsh[j] = sc;
        scsh[H + j] = fmaf(-m, sc, b[j]);
    }
}

// ---------------- full MLP, one row per thread; max-pool over K via 16-lane
// shfl butterfly; each lane retains 4 of 64 pooled channels.
// NO min-waves clamp: let the allocator take ~128 VGPR with ZERO scratch
// (launch_bounds(256,4) pinned VGPR=64 and spilled ~GBs to scratch).
// Grid: 3125 blocks * 256 thr * 4 iters == 3,200,000 rows exactly (no tail).
__global__ __launch_bounds__(256) void k_pool2(
    const float* __restrict__ p, const float4* __restrict__ f,
    const int* __restrict__ gidx,
    const float* __restrict__ w1, const float* __restrict__ w2,
    const float* __restrict__ w3,
    const float* __restrict__ scsh1, const float* __restrict__ scsh2,
    float* __restrict__ stats, float* __restrict__ pooled)
{
    __shared__ __align__(16) float w1s[112];
    __shared__ __align__(16) float w2s[512];
    __shared__ __align__(16) float w3s[2048];
    __shared__ float sc1s[16], sh1s[16], sc2s[32], sh2s[32];
    __shared__ float reds[256];
    __shared__ float redq[256];
    int tid = threadIdx.x;
    for (int i = tid; i < 112; i += 256) w1s[i] = w1[i];
    for (int i = tid; i < 512; i += 256) w2s[i] = w2[i];
    for (int i = tid; i < 2048; i += 256) w3s[i] = w3[i];
    if (tid < 16) { sc1s[tid] = scsh1[tid]; sh1s[tid] = scsh1[16 + tid]; }
    if (tid < 32) { sc2s[tid] = scsh2[tid]; sh2s[tid] = scsh2[32 + tid]; }
    __syncthreads();

    const float4* w1v = (const float4*)w1s;   // [7][4]
    const float4* w2v = (const float4*)w2s;   // [16][8]
    const float4* w3v = (const float4*)w3s;   // [32][16]

    int lane = tid & 63;
    int sub  = lane & 15;   // this lane keeps channels [4*sub, 4*sub+3]

    float s0 = 0.f, s1 = 0.f, s2 = 0.f, s3 = 0.f;
    float q0 = 0.f, q1 = 0.f, q2 = 0.f, q3 = 0.f;

    const int stride = 3125 * 256;  // 800000
#pragma unroll 1
    for (int r = blockIdx.x * 256 + tid; r < MROWS; r += stride) {
        int n = r >> 4;                 // point; its 16 rows sit in 16 consecutive lanes
        int idx = gidx[r];              // fully coalesced
        float4 fv = f[idx];
        float x[7];
        x[0] = p[idx * 3 + 0] - p[n * 3 + 0];
        x[1] = p[idx * 3 + 1] - p[n * 3 + 1];
        x[2] = p[idx * 3 + 2] - p[n * 3 + 2];
        x[3] = fv.x; x[4] = fv.y; x[5] = fv.z; x[6] = fv.w;

        float h1[16];
#pragma unroll
        for (int j0 = 0; j0 < 16; j0 += 4) {
            float y0 = 0.f, y1 = 0.f, y2 = 0.f, y3 = 0.f;
#pragma unroll
            for (int i = 0; i < 7; i++) {
                float4 w = w1v[i * 4 + (j0 >> 2)];
                float xi = x[i];
                y0 = fmaf(xi, w.x, y0); y1 = fmaf(xi, w.y, y1);
                y2 = fmaf(xi, w.z, y2); y3 = fmaf(xi, w.w, y3);
            }
            h1[j0 + 0] = gelu_f(fmaf(y0, sc1s[j0 + 0], sh1s[j0 + 0]));
            h1[j0 + 1] = gelu_f(fmaf(y1, sc1s[j0 + 1], sh1s[j0 + 1]));
            h1[j0 + 2] = gelu_f(fmaf(y2, sc1s[j0 + 2], sh1s[j0 + 2]));
            h1[j0 + 3] = gelu_f(fmaf(y3, sc1s[j0 + 3], sh1s[j0 + 3]));
        }
        float h2[32];
#pragma unroll
        for (int j0 = 0; j0 < 32; j0 += 4) {
            float y0 = 0.f, y1 = 0.f, y2 = 0.f, y3 = 0.f;
#pragma unroll
            for (int i = 0; i < 16; i++) {
                float4 w = w2v[i * 8 + (j0 >> 2)];
                float hi = h1[i];
                y0 = fmaf(hi, w.x, y0); y1 = fmaf(hi, w.y, y1);
                y2 = fmaf(hi, w.z, y2); y3 = fmaf(hi, w.w, y3);
            }
            h2[j0 + 0] = gelu_f(fmaf(y0, sc2s[j0 + 0], sh2s[j0 + 0]));
            h2[j0 + 1] = gelu_f(fmaf(y1, sc2s[j0 + 1], sh2s[j0 + 1]));
            h2[j0 + 2] = gelu_f(fmaf(y2, sc2s[j0 + 2], sh2s[j0 + 2]));
            h2[j0 + 3] = gelu_f(fmaf(y3, sc2s[j0 + 3], sh2s[j0 + 3]));
        }

        float pv0 = 0.f, pv1 = 0.f, pv2 = 0.f, pv3 = 0.f;
#pragma unroll
        for (int c = 0; c < 16; c++) {
            float y0 = 0.f, y1 = 0.f, y2 = 0.f, y3 = 0.f;
#pragma unroll
            for (int i = 0; i < 32; i++) {
                float4 w = w3v[i * 16 + c];   // wave-uniform -> LDS broadcast
                float h = h2[i];
                y0 = fmaf(h, w.x, y0); y1 = fmaf(h, w.y, y1);
                y2 = fmaf(h, w.z, y2); y3 = fmaf(h, w.w, y3);
            }
            // max over the point's 16 rows (lanes l0..l0+15)
#pragma unroll
            for (int m = 1; m <= 8; m <<= 1) {
                y0 = fmaxf(y0, __shfl_xor(y0, m));
                y1 = fmaxf(y1, __shfl_xor(y1, m));
                y2 = fmaxf(y2, __shfl_xor(y2, m));
                y3 = fmaxf(y3, __shfl_xor(y3, m));
            }
            if (sub == c) { pv0 = y0; pv1 = y1; pv2 = y2; pv3 = y3; }
        }
        // 16 lanes cover point n's 64 channels contiguously -> coalesced
        *(float4*)&pooled[(size_t)n * 64 + sub * 4] = make_float4(pv0, pv1, pv2, pv3);
        s0 += pv0; q0 = fmaf(pv0, pv0, q0);
        s1 += pv1; q1 = fmaf(pv1, pv1, q1);
        s2 += pv2; q2 = fmaf(pv2, pv2, q2);
        s3 += pv3; q3 = fmaf(pv3, pv3, q3);
    }

    // fold lanes l+16,l+32,l+48 into lanes 0..15 (same channel set)
    s0 += __shfl_down(s0, 32); s0 += __shfl_down(s0, 16);
    s1 += __shfl_down(s1, 32); s1 += __shfl_down(s1, 16);
    s2 += __shfl_down(s2, 32); s2 += __shfl_down(s2, 16);
    s3 += __shfl_down(s3, 32); s3 += __shfl_down(s3, 16);
    q0 += __shfl_down(q0, 32); q0 += __shfl_down(q0, 16);
    q1 += __shfl_down(q1, 32); q1 += __shfl_down(q1, 16);
    q2 += __shfl_down(q2, 32); q2 += __shfl_down(q2, 16);
    q3 += __shfl_down(q3, 32); q3 += __shfl_down(q3, 16);
    int wv = tid >> 6;
    if (lane < 16) {
        reds[wv * 64 + sub * 4 + 0] = s0;
        reds[wv * 64 + sub * 4 + 1] = s1;
        reds[wv * 64 + sub * 4 + 2] = s2;
        reds[wv * 64 + sub * 4 + 3] = s3;
        redq[wv * 64 + sub * 4 + 0] = q0;
        redq[wv * 64 + sub * 4 + 1] = q1;
        redq[wv * 64 + sub * 4 + 2] = q2;
        redq[wv * 64 + sub * 4 + 3] = q3;
    }
    __syncthreads();
    if (tid < 64) {
        atomicAdd(&stats[tid],
                  reds[tid] + reds[64 + tid] + reds[128 + tid] + reds[192 + tid]);
        atomicAdd(&stats[64 + tid],
                  redq[tid] + redq[64 + tid] + redq[128 + tid] + redq[192 + tid]);
    }
}

// double-BN collapse: z = a1*(y-m)+b_nbr has mean b_nbr, var a1^2*v exactly
__global__ void k_fin3(const float* __restrict__ stats,
                       const float* __restrict__ g_nbr, const float* __restrict__ g_post,
                       const float* __restrict__ b_post, float* __restrict__ scsh)
{
    int j = threadIdx.x;
    if (j < 64) {
        float m = stats[j] * (1.0f / NPTS);
        float v = stats[64 + j] * (1.0f / NPTS) - m * m;
        float a1 = g_nbr[j] * rsqrtf(v + EPSB);
        float s3 = g_post[j] * a1 * rsqrtf(fmaf(a1 * a1, v, EPSB));
        scsh[j] = s3;
        scsh[64 + j] = fmaf(-m, s3, b_post[j]);
    }
}

// ---------------- head: (N x 64) @ (64 x 256) ----------------
__global__ __launch_bounds__(256) void k_head(
    const float* __restrict__ pooled, const float* __restrict__ scsh3,
    const float* __restrict__ wpost, float* __restrict__ out)
{
    __shared__ float rowbuf[512];
    __shared__ float s3s[64], c3s[64];
    int tid = threadIdx.x;
    if (tid < 64) { s3s[tid] = scsh3[tid]; c3s[tid] = scsh3[64 + tid]; }
    float wcol[64];
#pragma unroll
    for (int j = 0; j < 64; j++) wcol[j] = wpost[j * 256 + tid];
    __syncthreads();

    const int nchunks = NPTS / 8;  // 25000
    for (int c = blockIdx.x; c < nchunks; c += gridDim.x) {
        int n0 = c * 8;
#pragma unroll
        for (int t = tid; t < 512; t += 256) {
            int rr = t >> 6, j = t & 63;
            rowbuf[t] = fmaf(pooled[(size_t)(n0 + rr) * 64 + j], s3s[j], c3s[j]);
        }
        __syncthreads();
#pragma unroll
        for (int rr = 0; rr < 8; rr++) {
            float acc = 0.f;
#pragma unroll
            for (int j = 0; j < 64; j++) acc = fmaf(rowbuf[rr * 64 + j], wcol[j], acc);
            out[(size_t)(n0 + rr) * 256 + tid] = acc;
        }
        __syncthreads();
    }
}

extern "C" void kernel_launch(void* const* d_in, const int* in_sizes, int n_in,
                              void* d_out, int out_size, void* d_ws, size_t ws_size,
                              hipStream_t stream)
{
    const float*  p    = (const float*)d_in[0];
    const float4* f    = (const float4*)d_in[1];
    const int*    gidx = (const int*)d_in[2];
    const float*  w1   = (const float*)d_in[3];
    const float*  g1   = (const float*)d_in[4];
    const float*  b1   = (const float*)d_in[5];
    const float*  w2   = (const float*)d_in[6];
    const float*  g2   = (const float*)d_in[7];
    const float*  b2   = (const float*)d_in[8];
    const float*  w3   = (const float*)d_in[9];
    const float*  gn   = (const float*)d_in[10];
    // d_in[11] = b_nbr: cancels exactly in the collapsed double-BN
    const float*  gp   = (const float*)d_in[12];
    const float*  bp   = (const float*)d_in[13];
    const float*  wp   = (const float*)d_in[14];
    float* out = (float*)d_out;
    float* ws  = (float*)d_ws;

    float* stats1 = ws;        float* scsh1 = ws + 32;
    float* stats2 = ws + 64;   float* scsh2 = ws + 128;
    float* stats3 = ws + 192;  float* scsh3 = ws + 320;
    float* pooled = ws + 1024;

    hipMemsetAsync(d_ws, 0, 2048, stream);
    k_stats1<<<2048, 256, 0, stream>>>(p, f, gidx, w1, stats1);
    k_finalize<<<1, 64, 0, stream>>>(stats1, g1, b1, scsh1, 16, 1.0f / (float)MROWS);
    k_stats2<<<2048, 256, 0, stream>>>(p, f, gidx, w1, w2, scsh1, stats2);
    k_finalize<<<1, 64, 0, stream>>>(stats2, g2, b2, scsh2, 32, 1.0f / (float)MROWS);
    k_pool2<<<3125, 256, 0, stream>>>(p, f, gidx, w1, w2, w3, scsh1, scsh2, stats3, pooled);
    k_fin3<<<1, 64, 0, stream>>>(stats3, gn, gp, bp, scsh3);
    k_head<<<1024, 256, 0, stream>>>(pooled, scsh3, wp, out);
}

// Round 5
// 1627.903 us; speedup vs baseline: 2.7388x; 1.8421x over previous
//
#include <hip/hip_runtime.h>
#include <cmath>

#define NPTS  200000
#define KNBR  16
#define MROWS 3200000   // NPTS*KNBR
#define EPSB  1e-5f
#define H2LD  260       // h2t row stride in floats (pad 256->260: 16B-aligned, kills 4-way conflicts)

__device__ __forceinline__ float gelu_f(float x) {
    return 0.5f * x * (1.0f + erff(x * 0.70710678118654752f));
}

// ---------------- stats over x itself: sum x (7) + sum x x^T (28) ----------------
// y1 = x @ w1 is linear, so BN1 mean/var follow from these 35 moments.
__global__ __launch_bounds__(256) void k_stats1(
    const float* __restrict__ p, const float4* __restrict__ f,
    const int* __restrict__ gidx, float* __restrict__ stats)
{
    __shared__ float red[4 * 35];

    float acc[35];
#pragma unroll
    for (int c = 0; c < 35; c++) acc[c] = 0.f;

    int stride = gridDim.x * 256;
    for (int r = blockIdx.x * 256 + threadIdx.x; r < MROWS; r += stride) {
        int n = r >> 4;
        int idx = gidx[r];
        float4 fv = f[idx];
        float x[7];
        x[0] = p[idx * 3 + 0] - p[n * 3 + 0];
        x[1] = p[idx * 3 + 1] - p[n * 3 + 1];
        x[2] = p[idx * 3 + 2] - p[n * 3 + 2];
        x[3] = fv.x; x[4] = fv.y; x[5] = fv.z; x[6] = fv.w;
#pragma unroll
        for (int i = 0; i < 7; i++) acc[i] += x[i];
        int t = 7;
#pragma unroll
        for (int i = 0; i < 7; i++)
#pragma unroll
            for (int l = i; l < 7; l++) { acc[t] = fmaf(x[i], x[l], acc[t]); t++; }
    }
    int lane = threadIdx.x & 63, wv = threadIdx.x >> 6;
#pragma unroll
    for (int c = 0; c < 35; c++) {
        float v = acc[c];
        v += __shfl_down(v, 32); v += __shfl_down(v, 16); v += __shfl_down(v, 8);
        v += __shfl_down(v, 4);  v += __shfl_down(v, 2);  v += __shfl_down(v, 1);
        if (lane == 0) red[wv * 35 + c] = v;
    }
    __syncthreads();
    for (int c = threadIdx.x; c < 35; c += 256)
        atomicAdd(&stats[c], red[c] + red[35 + c] + red[70 + c] + red[105 + c]);
}

// BN1 finalize from x-moments: mean_j = w_j . mx ; E[y^2]_j = w_j^T Mxx w_j
__global__ void k_fin1(const float* __restrict__ stats, const float* __restrict__ w1,
                       const float* __restrict__ g, const float* __restrict__ b,
                       float* __restrict__ scsh)
{
    int j = threadIdx.x;
    if (j < 16) {
        const float invM = 1.0f / (float)MROWS;
        float w[7];
#pragma unroll
        for (int i = 0; i < 7; i++) w[i] = w1[i * 16 + j];
        float m = 0.f;
#pragma unroll
        for (int i = 0; i < 7; i++) m = fmaf(w[i], stats[i], m);
        m *= invM;
        float e2 = 0.f;
        int t = 7;
#pragma unroll
        for (int i = 0; i < 7; i++)
#pragma unroll
            for (int l = i; l < 7; l++) {
                float coeff = (i == l) ? 1.0f : 2.0f;
                e2 = fmaf(coeff * w[i] * w[l], stats[t], e2);
                t++;
            }
        e2 *= invM;
        float v = e2 - m * m;
        float sc = g[j] * rsqrtf(v + EPSB);
        scsh[j] = sc;
        scsh[16 + j] = fmaf(-m, sc, b[j]);
    }
}

// ---------------- stats over y2 = gelu(bn(y1)) @ w2 (32 ch) ----------------
__global__ __launch_bounds__(256) void k_stats2(
    const float* __restrict__ p, const float4* __restrict__ f,
    const int* __restrict__ gidx, const float* __restrict__ w1,
    const float* __restrict__ w2, const float* __restrict__ scsh1,
    float* __restrict__ stats)
{
    __shared__ __align__(16) float w1s[112];
    __shared__ __align__(16) float w2s[512];
    __shared__ float sc1s[16], sh1s[16];
    __shared__ float red[4 * 64];
    for (int i = threadIdx.x; i < 112; i += 256) w1s[i] = w1[i];
    for (int i = threadIdx.x; i < 512; i += 256) w2s[i] = w2[i];
    if (threadIdx.x < 16) {
        sc1s[threadIdx.x] = scsh1[threadIdx.x];
        sh1s[threadIdx.x] = scsh1[16 + threadIdx.x];
    }
    __syncthreads();
    const float4* w1v = (const float4*)w1s;   // [7][4]
    const float4* w2v = (const float4*)w2s;   // [16][8]

    float acc[64];
#pragma unroll
    for (int c = 0; c < 64; c++) acc[c] = 0.f;

    int stride = gridDim.x * 256;
    for (int r = blockIdx.x * 256 + threadIdx.x; r < MROWS; r += stride) {
        int n = r >> 4;
        int idx = gidx[r];
        float4 fv = f[idx];
        float x[7];
        x[0] = p[idx * 3 + 0] - p[n * 3 + 0];
        x[1] = p[idx * 3 + 1] - p[n * 3 + 1];
        x[2] = p[idx * 3 + 2] - p[n * 3 + 2];
        x[3] = fv.x; x[4] = fv.y; x[5] = fv.z; x[6] = fv.w;
        float h1[16];
#pragma unroll
        for (int j0 = 0; j0 < 16; j0 += 4) {
            float y0 = 0.f, y1 = 0.f, y2 = 0.f, y3 = 0.f;
#pragma unroll
            for (int i = 0; i < 7; i++) {
                float4 w = w1v[i * 4 + (j0 >> 2)];
                float xi = x[i];
                y0 = fmaf(xi, w.x, y0); y1 = fmaf(xi, w.y, y1);
                y2 = fmaf(xi, w.z, y2); y3 = fmaf(xi, w.w, y3);
            }
            h1[j0 + 0] = gelu_f(fmaf(y0, sc1s[j0 + 0], sh1s[j0 + 0]));
            h1[j0 + 1] = gelu_f(fmaf(y1, sc1s[j0 + 1], sh1s[j0 + 1]));
            h1[j0 + 2] = gelu_f(fmaf(y2, sc1s[j0 + 2], sh1s[j0 + 2]));
            h1[j0 + 3] = gelu_f(fmaf(y3, sc1s[j0 + 3], sh1s[j0 + 3]));
        }
#pragma unroll
        for (int j0 = 0; j0 < 32; j0 += 4) {
            float y0 = 0.f, y1 = 0.f, y2 = 0.f, y3 = 0.f;
#pragma unroll
            for (int i = 0; i < 16; i++) {
                float4 w = w2v[i * 8 + (j0 >> 2)];
                float hi = h1[i];
                y0 = fmaf(hi, w.x, y0); y1 = fmaf(hi, w.y, y1);
                y2 = fmaf(hi, w.z, y2); y3 = fmaf(hi, w.w, y3);
            }
            acc[j0 + 0] += y0; acc[32 + j0 + 0] += y0 * y0;
            acc[j0 + 1] += y1; acc[32 + j0 + 1] += y1 * y1;
            acc[j0 + 2] += y2; acc[32 + j0 + 2] += y2 * y2;
            acc[j0 + 3] += y3; acc[32 + j0 + 3] += y3 * y3;
        }
    }
    int lane = threadIdx.x & 63, wv = threadIdx.x >> 6;
#pragma unroll
    for (int c = 0; c < 64; c++) {
        float v = acc[c];
        v += __shfl_down(v, 32); v += __shfl_down(v, 16); v += __shfl_down(v, 8);
        v += __shfl_down(v, 4);  v += __shfl_down(v, 2);  v += __shfl_down(v, 1);
        if (lane == 0) red[wv * 64 + c] = v;
    }
    __syncthreads();
    for (int c = threadIdx.x; c < 64; c += 256)
        atomicAdd(&stats[c], red[c] + red[64 + c] + red[128 + c] + red[192 + c]);
}

// BN finalize: scale/shift from sum/sumsq
__global__ void k_finalize(const float* __restrict__ stats, const float* __restrict__ g,
                           const float* __restrict__ b, float* __restrict__ scsh,
                           int H, float invM)
{
    int j = threadIdx.x;
    if (j < H) {
        float m = stats[j] * invM;
        float v = stats[H + j] * invM - m * m;
        float sc = g[j] * rsqrtf(v + EPSB);
        scsh[j] = sc;
        scsh[H + j] = fmaf(-m, sc, b[j]);
    }
}

// ---------------- two-phase pool kernel ----------------
// Phase A (thread = row): compute h2[32], store TRANSPOSED to LDS h2t[32][H2LD].
// Phase B (thread = (pt = tid>>4, cc = tid&15)): layer3 for 4 channels of one
// point, maxing over its 16 neighbors read from h2t as float4 quads.
// No shuffles; DS ops/row ~halved; pooled writes coalesced.
// Grid: 3125 blocks * 256 thr * 4 iters == 3,200,000 rows exactly.
__global__ __launch_bounds__(256) void k_pool2(
    const float* __restrict__ p, const float4* __restrict__ f,
    const int* __restrict__ gidx,
    const float* __restrict__ w1, const float* __restrict__ w2,
    const float* __restrict__ w3,
    const float* __restrict__ scsh1, const float* __restrict__ scsh2,
    float* __restrict__ stats, float* __restrict__ pooled)
{
    __shared__ __align__(16) float w1s[112];
    __shared__ __align__(16) float w2s[512];
    __shared__ __align__(16) float w3s[2048];
    __shared__ __align__(16) float h2t[32 * H2LD];
    __shared__ float sc1s[16], sh1s[16], sc2s[32], sh2s[32];
    __shared__ float reds[256];
    __shared__ float redq[256];
    int tid = threadIdx.x;
    for (int i = tid; i < 112; i += 256) w1s[i] = w1[i];
    for (int i = tid; i < 512; i += 256) w2s[i] = w2[i];
    for (int i = tid; i < 2048; i += 256) w3s[i] = w3[i];
    if (tid < 16) { sc1s[tid] = scsh1[tid]; sh1s[tid] = scsh1[16 + tid]; }
    if (tid < 32) { sc2s[tid] = scsh2[tid]; sh2s[tid] = scsh2[32 + tid]; }
    __syncthreads();

    const float4* w1v = (const float4*)w1s;   // [7][4]
    const float4* w2v = (const float4*)w2s;   // [16][8]
    const float4* w3v = (const float4*)w3s;   // [32][16]

    int lane = tid & 63;
    int pt = tid >> 4;      // phase-B point (0..15)
    int cc = tid & 15;      // phase-B channel chunk: channels [4cc, 4cc+3]

    float s0 = 0.f, s1 = 0.f, s2 = 0.f, s3 = 0.f;
    float q0 = 0.f, q1 = 0.f, q2 = 0.f, q3 = 0.f;

#pragma unroll 1
    for (int it = 0; it < 4; it++) {
        // ---------- phase A: one row per thread ----------
        int r = it * 800000 + blockIdx.x * 256 + tid;
        int n = r >> 4;
        int idx = gidx[r];
        float4 fv = f[idx];
        float x[7];
        x[0] = p[idx * 3 + 0] - p[n * 3 + 0];
        x[1] = p[idx * 3 + 1] - p[n * 3 + 1];
        x[2] = p[idx * 3 + 2] - p[n * 3 + 2];
        x[3] = fv.x; x[4] = fv.y; x[5] = fv.z; x[6] = fv.w;

        float h1[16];
#pragma unroll
        for (int j0 = 0; j0 < 16; j0 += 4) {
            float y0 = 0.f, y1 = 0.f, y2 = 0.f, y3 = 0.f;
#pragma unroll
            for (int i = 0; i < 7; i++) {
                float4 w = w1v[i * 4 + (j0 >> 2)];
                float xi = x[i];
                y0 = fmaf(xi, w.x, y0); y1 = fmaf(xi, w.y, y1);
                y2 = fmaf(xi, w.z, y2); y3 = fmaf(xi, w.w, y3);
            }
            h1[j0 + 0] = gelu_f(fmaf(y0, sc1s[j0 + 0], sh1s[j0 + 0]));
            h1[j0 + 1] = gelu_f(fmaf(y1, sc1s[j0 + 1], sh1s[j0 + 1]));
            h1[j0 + 2] = gelu_f(fmaf(y2, sc1s[j0 + 2], sh1s[j0 + 2]));
            h1[j0 + 3] = gelu_f(fmaf(y3, sc1s[j0 + 3], sh1s[j0 + 3]));
        }
#pragma unroll
        for (int j0 = 0; j0 < 32; j0 += 4) {
            float y0 = 0.f, y1 = 0.f, y2 = 0.f, y3 = 0.f;
#pragma unroll
            for (int i = 0; i < 16; i++) {
                float4 w = w2v[i * 8 + (j0 >> 2)];
                float hi = h1[i];
                y0 = fmaf(hi, w.x, y0); y1 = fmaf(hi, w.y, y1);
                y2 = fmaf(hi, w.z, y2); y3 = fmaf(hi, w.w, y3);
            }
            // transposed store: h2t[channel][local_row]; lanes write consecutive
            // addresses -> conflict-free
            h2t[(j0 + 0) * H2LD + tid] = gelu_f(fmaf(y0, sc2s[j0 + 0], sh2s[j0 + 0]));
            h2t[(j0 + 1) * H2LD + tid] = gelu_f(fmaf(y1, sc2s[j0 + 1], sh2s[j0 + 1]));
            h2t[(j0 + 2) * H2LD + tid] = gelu_f(fmaf(y2, sc2s[j0 + 2], sh2s[j0 + 2]));
            h2t[(j0 + 3) * H2LD + tid] = gelu_f(fmaf(y3, sc2s[j0 + 3], sh2s[j0 + 3]));
        }
        __syncthreads();

        // ---------- phase B: (point, channel-chunk) per thread ----------
        float m0 = -3.0e38f, m1 = -3.0e38f, m2 = -3.0e38f, m3 = -3.0e38f;
#pragma unroll 1
        for (int qd = 0; qd < 4; qd++) {          // 4 neighbors at a time
            int rb = (pt << 4) + (qd << 2);       // local row base
            float a00 = 0.f, a01 = 0.f, a02 = 0.f, a03 = 0.f;
            float a10 = 0.f, a11 = 0.f, a12 = 0.f, a13 = 0.f;
            float a20 = 0.f, a21 = 0.f, a22 = 0.f, a23 = 0.f;
            float a30 = 0.f, a31 = 0.f, a32 = 0.f, a33 = 0.f;
#pragma unroll 8
            for (int i = 0; i < 32; i++) {
                float4 hv = *(const float4*)&h2t[i * H2LD + rb];   // 4 nbrs, ch i
                float4 wf = w3v[i * 16 + cc];                       // 4 out-ch
                a00 = fmaf(hv.x, wf.x, a00); a01 = fmaf(hv.x, wf.y, a01);
                a02 = fmaf(hv.x, wf.z, a02); a03 = fmaf(hv.x, wf.w, a03);
                a10 = fmaf(hv.y, wf.x, a10); a11 = fmaf(hv.y, wf.y, a11);
                a12 = fmaf(hv.y, wf.z, a12); a13 = fmaf(hv.y, wf.w, a13);
                a20 = fmaf(hv.z, wf.x, a20); a21 = fmaf(hv.z, wf.y, a21);
                a22 = fmaf(hv.z, wf.z, a22); a23 = fmaf(hv.z, wf.w, a23);
                a30 = fmaf(hv.w, wf.x, a30); a31 = fmaf(hv.w, wf.y, a31);
                a32 = fmaf(hv.w, wf.z, a32); a33 = fmaf(hv.w, wf.w, a33);
            }
            m0 = fmaxf(fmaxf(fmaxf(m0, a00), fmaxf(a10, a20)), a30);
            m1 = fmaxf(fmaxf(fmaxf(m1, a01), fmaxf(a11, a21)), a31);
            m2 = fmaxf(fmaxf(fmaxf(m2, a02), fmaxf(a12, a22)), a32);
            m3 = fmaxf(fmaxf(fmaxf(m3, a03), fmaxf(a13, a23)), a33);
        }
        int np = it * 50000 + blockIdx.x * 16 + pt;
        *(float4*)&pooled[(size_t)np * 64 + cc * 4] = make_float4(m0, m1, m2, m3);
        s0 += m0; q0 = fmaf(m0, m0, q0);
        s1 += m1; q1 = fmaf(m1, m1, q1);
        s2 += m2; q2 = fmaf(m2, m2, q2);
        s3 += m3; q3 = fmaf(m3, m3, q3);
        __syncthreads();   // protect h2t before next iteration's writes
    }

    // stats fold: lanes cc, cc+16, cc+32, cc+48 hold different points, same channels
    s0 += __shfl_down(s0, 32); s0 += __shfl_down(s0, 16);
    s1 += __shfl_down(s1, 32); s1 += __shfl_down(s1, 16);
    s2 += __shfl_down(s2, 32); s2 += __shfl_down(s2, 16);
    s3 += __shfl_down(s3, 32); s3 += __shfl_down(s3, 16);
    q0 += __shfl_down(q0, 32); q0 += __shfl_down(q0, 16);
    q1 += __shfl_down(q1, 32); q1 += __shfl_down(q1, 16);
    q2 += __shfl_down(q2, 32); q2 += __shfl_down(q2, 16);
    q3 += __shfl_down(q3, 32); q3 += __shfl_down(q3, 16);
    int wv = tid >> 6;
    if (lane < 16) {
        reds[wv * 64 + lane * 4 + 0] = s0;
        reds[wv * 64 + lane * 4 + 1] = s1;
        reds[wv * 64 + lane * 4 + 2] = s2;
        reds[wv * 64 + lane * 4 + 3] = s3;
        redq[wv * 64 + lane * 4 + 0] = q0;
        redq[wv * 64 + lane * 4 + 1] = q1;
        redq[wv * 64 + lane * 4 + 2] = q2;
        redq[wv * 64 + lane * 4 + 3] = q3;
    }
    __syncthreads();
    if (tid < 64) {
        atomicAdd(&stats[tid],
                  reds[tid] + reds[64 + tid] + reds[128 + tid] + reds[192 + tid]);
        atomicAdd(&stats[64 + tid],
                  redq[tid] + redq[64 + tid] + redq[128 + tid] + redq[192 + tid]);
    }
}

// double-BN collapse: z = a1*(y-m)+b_nbr has mean b_nbr, var a1^2*v exactly
__global__ void k_fin3(const float* __restrict__ stats,
                       const float* __restrict__ g_nbr, const float* __restrict__ g_post,
                       const float* __restrict__ b_post, float* __restrict__ scsh)
{
    int j = threadIdx.x;
    if (j < 64) {
        float m = stats[j] * (1.0f / NPTS);
        float v = stats[64 + j] * (1.0f / NPTS) - m * m;
        float a1 = g_nbr[j] * rsqrtf(v + EPSB);
        float s3 = g_post[j] * a1 * rsqrtf(fmaf(a1 * a1, v, EPSB));
        scsh[j] = s3;
        scsh[64 + j] = fmaf(-m, s3, b_post[j]);
    }
}

// ---------------- head: (N x 64) @ (64 x 256) ----------------
__global__ __launch_bounds__(256) void k_head(
    const float* __restrict__ pooled, const float* __restrict__ scsh3,
    const float* __restrict__ wpost, float* __restrict__ out)
{
    __shared__ float rowbuf[512];
    __shared__ float s3s[64], c3s[64];
    int tid = threadIdx.x;
    if (tid < 64) { s3s[tid] = scsh3[tid]; c3s[tid] = scsh3[64 + tid]; }
    float wcol[64];
#pragma unroll
    for (int j = 0; j < 64; j++) wcol[j] = wpost[j * 256 + tid];
    __syncthreads();

    const int nchunks = NPTS / 8;  // 25000
    for (int c = blockIdx.x; c < nchunks; c += gridDim.x) {
        int n0 = c * 8;
#pragma unroll
        for (int t = tid; t < 512; t += 256) {
            int rr = t >> 6, j = t & 63;
            rowbuf[t] = fmaf(pooled[(size_t)(n0 + rr) * 64 + j], s3s[j], c3s[j]);
        }
        __syncthreads();
#pragma unroll
        for (int rr = 0; rr < 8; rr++) {
            float acc = 0.f;
#pragma unroll
            for (int j = 0; j < 64; j++) acc = fmaf(rowbuf[rr * 64 + j], wcol[j], acc);
            out[(size_t)(n0 + rr) * 256 + tid] = acc;
        }
        __syncthreads();
    }
}

extern "C" void kernel_launch(void* const* d_in, const int* in_sizes, int n_in,
                              void* d_out, int out_size, void* d_ws, size_t ws_size,
                              hipStream_t stream)
{
    const float*  p    = (const float*)d_in[0];
    const float4* f    = (const float4*)d_in[1];
    const int*    gidx = (const int*)d_in[2];
    const float*  w1   = (const float*)d_in[3];
    const float*  g1   = (const float*)d_in[4];
    const float*  b1   = (const float*)d_in[5];
    const float*  w2   = (const float*)d_in[6];
    const float*  g2   = (const float*)d_in[7];
    const float*  b2   = (const float*)d_in[8];
    const float*  w3   = (const float*)d_in[9];
    const float*  gn   = (const float*)d_in[10];
    // d_in[11] = b_nbr: cancels exactly in the collapsed double-BN
    const float*  gp   = (const float*)d_in[12];
    const float*  bp   = (const float*)d_in[13];
    const float*  wp   = (const float*)d_in[14];
    float* out = (float*)d_out;
    float* ws  = (float*)d_ws;

    float* stats1 = ws;          // 35 floats (x moments)
    float* scsh1  = ws + 40;     // 32
    float* stats2 = ws + 80;     // 64
    float* scsh2  = ws + 144;    // 64
    float* stats3 = ws + 208;    // 128
    float* scsh3  = ws + 336;    // 128
    float* pooled = ws + 1024;

    hipMemsetAsync(d_ws, 0, 2048, stream);
    k_stats1<<<2048, 256, 0, stream>>>(p, f, gidx, stats1);
    k_fin1<<<1, 64, 0, stream>>>(stats1, w1, g1, b1, scsh1);
    k_stats2<<<2048, 256, 0, stream>>>(p, f, gidx, w1, w2, scsh1, stats2);
    k_finalize<<<1, 64, 0, stream>>>(stats2, g2, b2, scsh2, 32, 1.0f / (float)MROWS);
    k_pool2<<<3125, 256, 0, stream>>>(p, f, gidx, w1, w2, w3, scsh1, scsh2, stats3, pooled);
    k_fin3<<<1, 64, 0, stream>>>(stats3, gn, gp, bp, scsh3);
    k_head<<<1024, 256, 0, stream>>>(pooled, scsh3, wp, out);
}

// Round 6
// 1258.550 us; speedup vs baseline: 3.5426x; 1.2935x over previous
//
#include <hip/hip_runtime.h>
#include <cmath>

#define NPTS  200000
#define KNBR  16
#define MROWS 3200000   // NPTS*KNBR
#define EPSB  1e-5f
#define H2LD  260       // h2t row stride in floats (pad 256->260: 16B-aligned, kills 4-way conflicts)

__device__ __forceinline__ float gelu_f(float x) {
    return 0.5f * x * (1.0f + erff(x * 0.70710678118654752f));
}

// ---------------- stats over x itself: sum x (7) + sum x x^T (28) ----------------
// y1 = x @ w1 is linear, so BN1 mean/var follow from these 35 moments.
__global__ __launch_bounds__(256) void k_stats1(
    const float* __restrict__ p, const float4* __restrict__ f,
    const int* __restrict__ gidx, float* __restrict__ stats)
{
    __shared__ float red[4 * 35];

    float acc[35];
#pragma unroll
    for (int c = 0; c < 35; c++) acc[c] = 0.f;

    int stride = gridDim.x * 256;
    for (int r = blockIdx.x * 256 + threadIdx.x; r < MROWS; r += stride) {
        int n = r >> 4;
        int idx = gidx[r];
        float4 fv = f[idx];
        float x[7];
        x[0] = p[idx * 3 + 0] - p[n * 3 + 0];
        x[1] = p[idx * 3 + 1] - p[n * 3 + 1];
        x[2] = p[idx * 3 + 2] - p[n * 3 + 2];
        x[3] = fv.x; x[4] = fv.y; x[5] = fv.z; x[6] = fv.w;
#pragma unroll
        for (int i = 0; i < 7; i++) acc[i] += x[i];
        int t = 7;
#pragma unroll
        for (int i = 0; i < 7; i++)
#pragma unroll
            for (int l = i; l < 7; l++) { acc[t] = fmaf(x[i], x[l], acc[t]); t++; }
    }
    int lane = threadIdx.x & 63, wv = threadIdx.x >> 6;
#pragma unroll
    for (int c = 0; c < 35; c++) {
        float v = acc[c];
        v += __shfl_down(v, 32); v += __shfl_down(v, 16); v += __shfl_down(v, 8);
        v += __shfl_down(v, 4);  v += __shfl_down(v, 2);  v += __shfl_down(v, 1);
        if (lane == 0) red[wv * 35 + c] = v;
    }
    __syncthreads();
    for (int c = threadIdx.x; c < 35; c += 256)
        atomicAdd(&stats[c], red[c] + red[35 + c] + red[70 + c] + red[105 + c]);
}

// BN1 finalize from x-moments: mean_j = w_j . mx ; E[y^2]_j = w_j^T Mxx w_j
__global__ void k_fin1(const float* __restrict__ stats, const float* __restrict__ w1,
                       const float* __restrict__ g, const float* __restrict__ b,
                       float* __restrict__ scsh)
{
    int j = threadIdx.x;
    if (j < 16) {
        const float invM = 1.0f / (float)MROWS;
        float w[7];
#pragma unroll
        for (int i = 0; i < 7; i++) w[i] = w1[i * 16 + j];
        float m = 0.f;
#pragma unroll
        for (int i = 0; i < 7; i++) m = fmaf(w[i], stats[i], m);
        m *= invM;
        float e2 = 0.f;
        int t = 7;
#pragma unroll
        for (int i = 0; i < 7; i++)
#pragma unroll
            for (int l = i; l < 7; l++) {
                float coeff = (i == l) ? 1.0f : 2.0f;
                e2 = fmaf(coeff * w[i] * w[l], stats[t], e2);
                t++;
            }
        e2 *= invM;
        float v = e2 - m * m;
        float sc = g[j] * rsqrtf(v + EPSB);
        scsh[j] = sc;
        scsh[16 + j] = fmaf(-m, sc, b[j]);
    }
}

// ---------------- h1 moments, pass A: pairs (i,l), 0<=i<8, i<=l<16 -> 100 ----------------
// y2 = h1 @ w2 is linear in h1, so BN2 stats follow from h1 moments (no 64-acc spill).
__global__ __launch_bounds__(256) void k_stats2a(
    const float* __restrict__ p, const float4* __restrict__ f,
    const int* __restrict__ gidx, const float* __restrict__ w1,
    const float* __restrict__ scsh1, float* __restrict__ stats)
{
    __shared__ __align__(16) float w1s[112];
    __shared__ float sc1s[16], sh1s[16];
    __shared__ float red[4 * 100];
    for (int i = threadIdx.x; i < 112; i += 256) w1s[i] = w1[i];
    if (threadIdx.x < 16) {
        sc1s[threadIdx.x] = scsh1[threadIdx.x];
        sh1s[threadIdx.x] = scsh1[16 + threadIdx.x];
    }
    __syncthreads();
    const float4* w1v = (const float4*)w1s;   // [7][4]

    float acc[100];
#pragma unroll
    for (int c = 0; c < 100; c++) acc[c] = 0.f;

    int stride = gridDim.x * 256;
    for (int r = blockIdx.x * 256 + threadIdx.x; r < MROWS; r += stride) {
        int n = r >> 4;
        int idx = gidx[r];
        float4 fv = f[idx];
        float x[7];
        x[0] = p[idx * 3 + 0] - p[n * 3 + 0];
        x[1] = p[idx * 3 + 1] - p[n * 3 + 1];
        x[2] = p[idx * 3 + 2] - p[n * 3 + 2];
        x[3] = fv.x; x[4] = fv.y; x[5] = fv.z; x[6] = fv.w;
        float h1[16];
#pragma unroll
        for (int j0 = 0; j0 < 16; j0 += 4) {
            float y0 = 0.f, y1 = 0.f, y2 = 0.f, y3 = 0.f;
#pragma unroll
            for (int i = 0; i < 7; i++) {
                float4 w = w1v[i * 4 + (j0 >> 2)];
                float xi = x[i];
                y0 = fmaf(xi, w.x, y0); y1 = fmaf(xi, w.y, y1);
                y2 = fmaf(xi, w.z, y2); y3 = fmaf(xi, w.w, y3);
            }
            h1[j0 + 0] = gelu_f(fmaf(y0, sc1s[j0 + 0], sh1s[j0 + 0]));
            h1[j0 + 1] = gelu_f(fmaf(y1, sc1s[j0 + 1], sh1s[j0 + 1]));
            h1[j0 + 2] = gelu_f(fmaf(y2, sc1s[j0 + 2], sh1s[j0 + 2]));
            h1[j0 + 3] = gelu_f(fmaf(y3, sc1s[j0 + 3], sh1s[j0 + 3]));
        }
        int t = 0;
#pragma unroll
        for (int i = 0; i < 8; i++)
#pragma unroll
            for (int l = i; l < 16; l++) { acc[t] = fmaf(h1[i], h1[l], acc[t]); t++; }
    }
    int lane = threadIdx.x & 63, wv = threadIdx.x >> 6;
#pragma unroll
    for (int c = 0; c < 100; c++) {
        float v = acc[c];
        v += __shfl_down(v, 32); v += __shfl_down(v, 16); v += __shfl_down(v, 8);
        v += __shfl_down(v, 4);  v += __shfl_down(v, 2);  v += __shfl_down(v, 1);
        if (lane == 0) red[wv * 100 + c] = v;
    }
    __syncthreads();
    for (int c = threadIdx.x; c < 100; c += 256)
        atomicAdd(&stats[c], red[c] + red[100 + c] + red[200 + c] + red[300 + c]);
}

// ---------------- h1 moments, pass B: sums (16) + pairs (i,l), 8<=i<=l<16 (36) ----------------
__global__ __launch_bounds__(256) void k_stats2b(
    const float* __restrict__ p, const float4* __restrict__ f,
    const int* __restrict__ gidx, const float* __restrict__ w1,
    const float* __restrict__ scsh1, float* __restrict__ stats)
{
    __shared__ __align__(16) float w1s[112];
    __shared__ float sc1s[16], sh1s[16];
    __shared__ float red[4 * 52];
    for (int i = threadIdx.x; i < 112; i += 256) w1s[i] = w1[i];
    if (threadIdx.x < 16) {
        sc1s[threadIdx.x] = scsh1[threadIdx.x];
        sh1s[threadIdx.x] = scsh1[16 + threadIdx.x];
    }
    __syncthreads();
    const float4* w1v = (const float4*)w1s;   // [7][4]

    float acc[52];
#pragma unroll
    for (int c = 0; c < 52; c++) acc[c] = 0.f;

    int stride = gridDim.x * 256;
    for (int r = blockIdx.x * 256 + threadIdx.x; r < MROWS; r += stride) {
        int n = r >> 4;
        int idx = gidx[r];
        float4 fv = f[idx];
        float x[7];
        x[0] = p[idx * 3 + 0] - p[n * 3 + 0];
        x[1] = p[idx * 3 + 1] - p[n * 3 + 1];
        x[2] = p[idx * 3 + 2] - p[n * 3 + 2];
        x[3] = fv.x; x[4] = fv.y; x[5] = fv.z; x[6] = fv.w;
        float h1[16];
#pragma unroll
        for (int j0 = 0; j0 < 16; j0 += 4) {
            float y0 = 0.f, y1 = 0.f, y2 = 0.f, y3 = 0.f;
#pragma unroll
            for (int i = 0; i < 7; i++) {
                float4 w = w1v[i * 4 + (j0 >> 2)];
                float xi = x[i];
                y0 = fmaf(xi, w.x, y0); y1 = fmaf(xi, w.y, y1);
                y2 = fmaf(xi, w.z, y2); y3 = fmaf(xi, w.w, y3);
            }
            h1[j0 + 0] = gelu_f(fmaf(y0, sc1s[j0 + 0], sh1s[j0 + 0]));
            h1[j0 + 1] = gelu_f(fmaf(y1, sc1s[j0 + 1], sh1s[j0 + 1]));
            h1[j0 + 2] = gelu_f(fmaf(y2, sc1s[j0 + 2], sh1s[j0 + 2]));
            h1[j0 + 3] = gelu_f(fmaf(y3, sc1s[j0 + 3], sh1s[j0 + 3]));
        }
#pragma unroll
        for (int i = 0; i < 16; i++) acc[i] += h1[i];
        int t = 16;
#pragma unroll
        for (int i = 8; i < 16; i++)
#pragma unroll
            for (int l = i; l < 16; l++) { acc[t] = fmaf(h1[i], h1[l], acc[t]); t++; }
    }
    int lane = threadIdx.x & 63, wv = threadIdx.x >> 6;
#pragma unroll
    for (int c = 0; c < 52; c++) {
        float v = acc[c];
        v += __shfl_down(v, 32); v += __shfl_down(v, 16); v += __shfl_down(v, 8);
        v += __shfl_down(v, 4);  v += __shfl_down(v, 2);  v += __shfl_down(v, 1);
        if (lane == 0) red[wv * 52 + c] = v;
    }
    __syncthreads();
    for (int c = threadIdx.x; c < 52; c += 256)
        atomicAdd(&stats[100 + c], red[c] + red[52 + c] + red[104 + c] + red[156 + c]);
}

// BN2 finalize from h1 moments. stats layout: [0..99] pairs i<8, [100..115] sums,
// [116..151] pairs i>=8. mean_j = w2_j . S1 / M ; E[y^2]_j = w2_j^T M2 w2_j / M.
__global__ void k_fin2(const float* __restrict__ stats, const float* __restrict__ w2,
                       const float* __restrict__ g, const float* __restrict__ b,
                       float* __restrict__ scsh)
{
    int j = threadIdx.x;
    if (j < 32) {
        const float invM = 1.0f / (float)MROWS;
        float w[16];
#pragma unroll
        for (int i = 0; i < 16; i++) w[i] = w2[i * 32 + j];
        float m = 0.f;
#pragma unroll
        for (int i = 0; i < 16; i++) m = fmaf(w[i], stats[100 + i], m);
        m *= invM;
        float e2 = 0.f;
        int t = 0;
#pragma unroll
        for (int i = 0; i < 8; i++)
#pragma unroll
            for (int l = i; l < 16; l++) {
                float coeff = (i == l) ? 1.0f : 2.0f;
                e2 = fmaf(coeff * w[i] * w[l], stats[t], e2);
                t++;
            }
        t = 116;
#pragma unroll
        for (int i = 8; i < 16; i++)
#pragma unroll
            for (int l = i; l < 16; l++) {
                float coeff = (i == l) ? 1.0f : 2.0f;
                e2 = fmaf(coeff * w[i] * w[l], stats[t], e2);
                t++;
            }
        e2 *= invM;
        float v = e2 - m * m;
        float sc = g[j] * rsqrtf(v + EPSB);
        scsh[j] = sc;
        scsh[32 + j] = fmaf(-m, sc, b[j]);
    }
}

// ---------------- two-phase pool kernel ----------------
// Phase A (thread = row): compute h2[32], store TRANSPOSED to LDS h2t[32][H2LD].
// Phase B (thread = (pt = tid>>4, cc = tid&15)): layer3 for 4 channels of one
// point, maxing over its 16 neighbors read from h2t as float4 quads.
// No shuffles; DS ops/row ~halved; pooled writes coalesced.
// Grid: 3125 blocks * 256 thr * 4 iters == 3,200,000 rows exactly.
__global__ __launch_bounds__(256) void k_pool2(
    const float* __restrict__ p, const float4* __restrict__ f,
    const int* __restrict__ gidx,
    const float* __restrict__ w1, const float* __restrict__ w2,
    const float* __restrict__ w3,
    const float* __restrict__ scsh1, const float* __restrict__ scsh2,
    float* __restrict__ stats, float* __restrict__ pooled)
{
    __shared__ __align__(16) float w1s[112];
    __shared__ __align__(16) float w2s[512];
    __shared__ __align__(16) float w3s[2048];
    __shared__ __align__(16) float h2t[32 * H2LD];
    __shared__ float sc1s[16], sh1s[16], sc2s[32], sh2s[32];
    __shared__ float reds[256];
    __shared__ float redq[256];
    int tid = threadIdx.x;
    for (int i = tid; i < 112; i += 256) w1s[i] = w1[i];
    for (int i = tid; i < 512; i += 256) w2s[i] = w2[i];
    for (int i = tid; i < 2048; i += 256) w3s[i] = w3[i];
    if (tid < 16) { sc1s[tid] = scsh1[tid]; sh1s[tid] = scsh1[16 + tid]; }
    if (tid < 32) { sc2s[tid] = scsh2[tid]; sh2s[tid] = scsh2[32 + tid]; }
    __syncthreads();

    const float4* w1v = (const float4*)w1s;   // [7][4]
    const float4* w2v = (const float4*)w2s;   // [16][8]
    const float4* w3v = (const float4*)w3s;   // [32][16]

    int lane = tid & 63;
    int pt = tid >> 4;      // phase-B point (0..15)
    int cc = tid & 15;      // phase-B channel chunk: channels [4cc, 4cc+3]

    float s0 = 0.f, s1 = 0.f, s2 = 0.f, s3 = 0.f;
    float q0 = 0.f, q1 = 0.f, q2 = 0.f, q3 = 0.f;

#pragma unroll 1
    for (int it = 0; it < 4; it++) {
        // ---------- phase A: one row per thread ----------
        int r = it * 800000 + blockIdx.x * 256 + tid;
        int n = r >> 4;
        int idx = gidx[r];
        float4 fv = f[idx];
        float x[7];
        x[0] = p[idx * 3 + 0] - p[n * 3 + 0];
        x[1] = p[idx * 3 + 1] - p[n * 3 + 1];
        x[2] = p[idx * 3 + 2] - p[n * 3 + 2];
        x[3] = fv.x; x[4] = fv.y; x[5] = fv.z; x[6] = fv.w;

        float h1[16];
#pragma unroll
        for (int j0 = 0; j0 < 16; j0 += 4) {
            float y0 = 0.f, y1 = 0.f, y2 = 0.f, y3 = 0.f;
#pragma unroll
            for (int i = 0; i < 7; i++) {
                float4 w = w1v[i * 4 + (j0 >> 2)];
                float xi = x[i];
                y0 = fmaf(xi, w.x, y0); y1 = fmaf(xi, w.y, y1);
                y2 = fmaf(xi, w.z, y2); y3 = fmaf(xi, w.w, y3);
            }
            h1[j0 + 0] = gelu_f(fmaf(y0, sc1s[j0 + 0], sh1s[j0 + 0]));
            h1[j0 + 1] = gelu_f(fmaf(y1, sc1s[j0 + 1], sh1s[j0 + 1]));
            h1[j0 + 2] = gelu_f(fmaf(y2, sc1s[j0 + 2], sh1s[j0 + 2]));
            h1[j0 + 3] = gelu_f(fmaf(y3, sc1s[j0 + 3], sh1s[j0 + 3]));
        }
#pragma unroll
        for (int j0 = 0; j0 < 32; j0 += 4) {
            float y0 = 0.f, y1 = 0.f, y2 = 0.f, y3 = 0.f;
#pragma unroll
            for (int i = 0; i < 16; i++) {
                float4 w = w2v[i * 8 + (j0 >> 2)];
                float hi = h1[i];
                y0 = fmaf(hi, w.x, y0); y1 = fmaf(hi, w.y, y1);
                y2 = fmaf(hi, w.z, y2); y3 = fmaf(hi, w.w, y3);
            }
            // transposed store: h2t[channel][local_row]; lanes write consecutive
            // addresses -> conflict-free
            h2t[(j0 + 0) * H2LD + tid] = gelu_f(fmaf(y0, sc2s[j0 + 0], sh2s[j0 + 0]));
            h2t[(j0 + 1) * H2LD + tid] = gelu_f(fmaf(y1, sc2s[j0 + 1], sh2s[j0 + 1]));
            h2t[(j0 + 2) * H2LD + tid] = gelu_f(fmaf(y2, sc2s[j0 + 2], sh2s[j0 + 2]));
            h2t[(j0 + 3) * H2LD + tid] = gelu_f(fmaf(y3, sc2s[j0 + 3], sh2s[j0 + 3]));
        }
        __syncthreads();

        // ---------- phase B: (point, channel-chunk) per thread ----------
        float m0 = -3.0e38f, m1 = -3.0e38f, m2 = -3.0e38f, m3 = -3.0e38f;
#pragma unroll 1
        for (int qd = 0; qd < 4; qd++) {          // 4 neighbors at a time
            int rb = (pt << 4) + (qd << 2);       // local row base
            float a00 = 0.f, a01 = 0.f, a02 = 0.f, a03 = 0.f;
            float a10 = 0.f, a11 = 0.f, a12 = 0.f, a13 = 0.f;
            float a20 = 0.f, a21 = 0.f, a22 = 0.f, a23 = 0.f;
            float a30 = 0.f, a31 = 0.f, a32 = 0.f, a33 = 0.f;
#pragma unroll 8
            for (int i = 0; i < 32; i++) {
                float4 hv = *(const float4*)&h2t[i * H2LD + rb];   // 4 nbrs, ch i
                float4 wf = w3v[i * 16 + cc];                       // 4 out-ch
                a00 = fmaf(hv.x, wf.x, a00); a01 = fmaf(hv.x, wf.y, a01);
                a02 = fmaf(hv.x, wf.z, a02); a03 = fmaf(hv.x, wf.w, a03);
                a10 = fmaf(hv.y, wf.x, a10); a11 = fmaf(hv.y, wf.y, a11);
                a12 = fmaf(hv.y, wf.z, a12); a13 = fmaf(hv.y, wf.w, a13);
                a20 = fmaf(hv.z, wf.x, a20); a21 = fmaf(hv.z, wf.y, a21);
                a22 = fmaf(hv.z, wf.z, a22); a23 = fmaf(hv.z, wf.w, a23);
                a30 = fmaf(hv.w, wf.x, a30); a31 = fmaf(hv.w, wf.y, a31);
                a32 = fmaf(hv.w, wf.z, a32); a33 = fmaf(hv.w, wf.w, a33);
            }
            m0 = fmaxf(fmaxf(fmaxf(m0, a00), fmaxf(a10, a20)), a30);
            m1 = fmaxf(fmaxf(fmaxf(m1, a01), fmaxf(a11, a21)), a31);
            m2 = fmaxf(fmaxf(fmaxf(m2, a02), fmaxf(a12, a22)), a32);
            m3 = fmaxf(fmaxf(fmaxf(m3, a03), fmaxf(a13, a23)), a33);
        }
        int np = it * 50000 + blockIdx.x * 16 + pt;
        *(float4*)&pooled[(size_t)np * 64 + cc * 4] = make_float4(m0, m1, m2, m3);
        s0 += m0; q0 = fmaf(m0, m0, q0);
        s1 += m1; q1 = fmaf(m1, m1, q1);
        s2 += m2; q2 = fmaf(m2, m2, q2);
        s3 += m3; q3 = fmaf(m3, m3, q3);
        __syncthreads();   // protect h2t before next iteration's writes
    }

    // stats fold: lanes cc, cc+16, cc+32, cc+48 hold different points, same channels
    s0 += __shfl_down(s0, 32); s0 += __shfl_down(s0, 16);
    s1 += __shfl_down(s1, 32); s1 += __shfl_down(s1, 16);
    s2 += __shfl_down(s2, 32); s2 += __shfl_down(s2, 16);
    s3 += __shfl_down(s3, 32); s3 += __shfl_down(s3, 16);
    q0 += __shfl_down(q0, 32); q0 += __shfl_down(q0, 16);
    q1 += __shfl_down(q1, 32); q1 += __shfl_down(q1, 16);
    q2 += __shfl_down(q2, 32); q2 += __shfl_down(q2, 16);
    q3 += __shfl_down(q3, 32); q3 += __shfl_down(q3, 16);
    int wv = tid >> 6;
    if (lane < 16) {
        reds[wv * 64 + lane * 4 + 0] = s0;
        reds[wv * 64 + lane * 4 + 1] = s1;
        reds[wv * 64 + lane * 4 + 2] = s2;
        reds[wv * 64 + lane * 4 + 3] = s3;
        redq[wv * 64 + lane * 4 + 0] = q0;
        redq[wv * 64 + lane * 4 + 1] = q1;
        redq[wv * 64 + lane * 4 + 2] = q2;
        redq[wv * 64 + lane * 4 + 3] = q3;
    }
    __syncthreads();
    if (tid < 64) {
        atomicAdd(&stats[tid],
                  reds[tid] + reds[64 + tid] + reds[128 + tid] + reds[192 + tid]);
        atomicAdd(&stats[64 + tid],
                  redq[tid] + redq[64 + tid] + redq[128 + tid] + redq[192 + tid]);
    }
}

// double-BN collapse: z = a1*(y-m)+b_nbr has mean b_nbr, var a1^2*v exactly
__global__ void k_fin3(const float* __restrict__ stats,
                       const float* __restrict__ g_nbr, const float* __restrict__ g_post,
                       const float* __restrict__ b_post, float* __restrict__ scsh)
{
    int j = threadIdx.x;
    if (j < 64) {
        float m = stats[j] * (1.0f / NPTS);
        float v = stats[64 + j] * (1.0f / NPTS) - m * m;
        float a1 = g_nbr[j] * rsqrtf(v + EPSB);
        float s3 = g_post[j] * a1 * rsqrtf(fmaf(a1 * a1, v, EPSB));
        scsh[j] = s3;
        scsh[64 + j] = fmaf(-m, s3, b_post[j]);
    }
}

// ---------------- head: (N x 64) @ (64 x 256) ----------------
__global__ __launch_bounds__(256) void k_head(
    const float* __restrict__ pooled, const float* __restrict__ scsh3,
    const float* __restrict__ wpost, float* __restrict__ out)
{
    __shared__ float rowbuf[512];
    __shared__ float s3s[64], c3s[64];
    int tid = threadIdx.x;
    if (tid < 64) { s3s[tid] = scsh3[tid]; c3s[tid] = scsh3[64 + tid]; }
    float wcol[64];
#pragma unroll
    for (int j = 0; j < 64; j++) wcol[j] = wpost[j * 256 + tid];
    __syncthreads();

    const int nchunks = NPTS / 8;  // 25000
    for (int c = blockIdx.x; c < nchunks; c += gridDim.x) {
        int n0 = c * 8;
#pragma unroll
        for (int t = tid; t < 512; t += 256) {
            int rr = t >> 6, j = t & 63;
            rowbuf[t] = fmaf(pooled[(size_t)(n0 + rr) * 64 + j], s3s[j], c3s[j]);
        }
        __syncthreads();
#pragma unroll
        for (int rr = 0; rr < 8; rr++) {
            float acc = 0.f;
#pragma unroll
            for (int j = 0; j < 64; j++) acc = fmaf(rowbuf[rr * 64 + j], wcol[j], acc);
            out[(size_t)(n0 + rr) * 256 + tid] = acc;
        }
        __syncthreads();
    }
}

extern "C" void kernel_launch(void* const* d_in, const int* in_sizes, int n_in,
                              void* d_out, int out_size, void* d_ws, size_t ws_size,
                              hipStream_t stream)
{
    const float*  p    = (const float*)d_in[0];
    const float4* f    = (const float4*)d_in[1];
    const int*    gidx = (const int*)d_in[2];
    const float*  w1   = (const float*)d_in[3];
    const float*  g1   = (const float*)d_in[4];
    const float*  b1   = (const float*)d_in[5];
    const float*  w2   = (const float*)d_in[6];
    const float*  g2   = (const float*)d_in[7];
    const float*  b2   = (const float*)d_in[8];
    const float*  w3   = (const float*)d_in[9];
    const float*  gn   = (const float*)d_in[10];
    // d_in[11] = b_nbr: cancels exactly in the collapsed double-BN
    const float*  gp   = (const float*)d_in[12];
    const float*  bp   = (const float*)d_in[13];
    const float*  wp   = (const float*)d_in[14];
    float* out = (float*)d_out;
    float* ws  = (float*)d_ws;

    float* stats1 = ws;          // 35 floats (x moments)
    float* scsh1  = ws + 40;     // 32
    float* stats2 = ws + 80;     // 152 floats (h1 moments: 100 pairs + 16 sums + 36 pairs)
    float* scsh2  = ws + 240;    // 64
    float* stats3 = ws + 304;    // 128
    float* scsh3  = ws + 432;    // 128
    float* pooled = ws + 1024;

    hipMemsetAsync(d_ws, 0, 2048, stream);
    k_stats1<<<2048, 256, 0, stream>>>(p, f, gidx, stats1);
    k_fin1<<<1, 64, 0, stream>>>(stats1, w1, g1, b1, scsh1);
    k_stats2a<<<2048, 256, 0, stream>>>(p, f, gidx, w1, scsh1, stats2);
    k_stats2b<<<2048, 256, 0, stream>>>(p, f, gidx, w1, scsh1, stats2);
    k_fin2<<<1, 64, 0, stream>>>(stats2, w2, g2, b2, scsh2);
    k_pool2<<<3125, 256, 0, stream>>>(p, f, gidx, w1, w2, w3, scsh1, scsh2, stats3, pooled);
    k_fin3<<<1, 64, 0, stream>>>(stats3, gn, gp, bp, scsh3);
    k_head<<<1024, 256, 0, stream>>>(pooled, scsh3, wp, out);
}